// Round 2
// baseline (1705.512 us; speedup 1.0000x reference)
//
#include <hip/hip_runtime.h>
#include <math.h>

#define N_NODES 100000
#define N_EDGES 1600000
#define C_DIM 40
#define NGROUPS 6250                      // 100000 / 16 exactly

#define BSZ2 128                          // nodes per dst-bucket
#define NB2 ((N_NODES + BSZ2 - 1) / BSZ2) // 782
#define CAP 2560                          // bucket capacity: mean 2048, sd ~45 -> +11 sigma
#define EB  4096                          // edges per scatter block
#define NBE ((N_EDGES + EB - 1) / EB)     // 391

// ---------------- workspace layout (4-byte units) ----------------
#define OFF_DEG  0                        // float[100000] deg -> dinv (in place)
#define OFF_CNT  100000                   // int[800] bucket cursors
#define OFF_REC  100800                   // int2[NB2*CAP] = 2,001,920 recs (8B aligned)
#define OFF_H1P  4104640                  // ushort[N*64] bf16 h1 (unscaled), 128B rows
#define OFF_H2P  7304640                  // ushort[N*40] bf16 h2 (unscaled), 80B packed rows
#define OFF_AGG1 9304640                  // float[N*64]

typedef float floatx4 __attribute__((ext_vector_type(4)));
typedef short shortx8 __attribute__((ext_vector_type(8)));

__device__ inline unsigned short f2bf(float f) {
    unsigned int u = __float_as_uint(f);
    u += 0x7FFF + ((u >> 16) & 1);        // round to nearest even
    return (unsigned short)(u >> 16);
}
__device__ inline float bflo(unsigned int u) { return __uint_as_float(u << 16); }
__device__ inline float bfhi(unsigned int u) { return __uint_as_float(u & 0xFFFF0000u); }

// ---------- fused degree-accumulate + bucket scatter (no sort, no hist) ----------
__global__ __launch_bounds__(512) void k_scatter2(const int* __restrict__ ei,
                                                  const float* __restrict__ w,
                                                  float* __restrict__ deg,
                                                  int* __restrict__ cnt,
                                                  int2* __restrict__ rec) {
    int t = threadIdx.x, b = blockIdx.x;
    int base = b * EB;
    for (int i = t; i < EB; i += 512) {
        int e = base + i;
        if (e < N_EDGES) {
            int s = ei[e], d = ei[N_EDGES + e];
            float wv = w[e];
            atomicAdd(&deg[d], wv);
            int bin = d >> 7;
            int pos = atomicAdd(&cnt[bin], 1);
            if (pos < CAP)
                rec[(long)bin * CAP + pos] =
                    make_int2(s | ((d & 127) << 17), __float_as_int(wv));
        }
    }
}

// ---------- dinv = rsqrt(1 + deg), in place ----------
__global__ __launch_bounds__(512) void k_dinv(float* __restrict__ deg) {
    int i = blockIdx.x * 512 + threadIdx.x;
    if (i < N_NODES) deg[i] = rsqrtf(1.f + deg[i]);
}

// ---------- h1 = x @ W1 via MFMA (UNscaled), stored bf16, 128B rows ----------
__global__ __launch_bounds__(256) void k_mm1(const float* __restrict__ x,
                                             const float* __restrict__ W1,
                                             unsigned short* __restrict__ h1p) {
    int t = threadIdx.x, lane = t & 63, wv = t >> 6;
    int m = lane & 15, quad = lane >> 4;
    int wid = blockIdx.x * 4 + wv, nw = gridDim.x * 4;
    shortx8 B[2][4];
#pragma unroll
    for (int kc = 0; kc < 2; ++kc)
#pragma unroll
        for (int tt = 0; tt < 4; ++tt)
#pragma unroll
            for (int j = 0; j < 8; ++j) {
                int k = kc * 32 + quad * 8 + j;
                B[kc][tt][j] = (short)f2bf(W1[k * 64 + tt * 16 + m]);
            }
    for (int g = wid; g < NGROUPS; g += nw) {
        int n0 = g * 16;
        const float* xr = x + (long)(n0 + m) * 64 + quad * 8;
        floatx4 xa = ((const floatx4*)xr)[0];
        floatx4 xb = ((const floatx4*)(xr + 4))[0];
        floatx4 xc = ((const floatx4*)(xr + 32))[0];
        floatx4 xd = ((const floatx4*)(xr + 36))[0];
        shortx8 A0, A1;
#pragma unroll
        for (int j = 0; j < 4; ++j) {
            A0[j] = (short)f2bf(xa[j]);
            A0[4 + j] = (short)f2bf(xb[j]);
            A1[j] = (short)f2bf(xc[j]);
            A1[4 + j] = (short)f2bf(xd[j]);
        }
        floatx4 acc[4];
#pragma unroll
        for (int tt = 0; tt < 4; ++tt) {
            acc[tt] = (floatx4){0.f, 0.f, 0.f, 0.f};
            acc[tt] = __builtin_amdgcn_mfma_f32_16x16x32_bf16(A0, B[0][tt], acc[tt], 0, 0, 0);
            acc[tt] = __builtin_amdgcn_mfma_f32_16x16x32_bf16(A1, B[1][tt], acc[tt], 0, 0, 0);
        }
#pragma unroll
        for (int reg = 0; reg < 4; ++reg) {
            int node = n0 + quad * 4 + reg;
#pragma unroll
            for (int tt = 0; tt < 4; ++tt)
                h1p[(long)node * 64 + tt * 16 + m] = f2bf(acc[tt][reg]);
        }
    }
}

// ---------- agg1: LDS-atomic bucket accumulation (128 nodes x 64 cols f32 = 32KB) ----------
// Wave-iter: 8 waves x 4 edge-groups x 2 slots = 64 edges/block-iter.
// Quad rotation (c + dstloc) & 3 breaks the deterministic 8-way ds_add bank conflict.
__global__ __launch_bounds__(512) void k_agg1b(const int* __restrict__ cnt,
                                               const int2* __restrict__ rec,
                                               const float* __restrict__ dinv,
                                               const unsigned short* __restrict__ h1p,
                                               float* __restrict__ agg1) {
    __shared__ float acc[BSZ2 * 64];      // 32 KB -> 4 blocks/CU, 100% occupancy
    int t = threadIdx.x, b = blockIdx.x;
    for (int i = t; i < BSZ2 * 64; i += 512) acc[i] = 0.f;
    __syncthreads();
    int cb = min(cnt[b], CAP);
    const int2* rbase = rec + (long)b * CAP;
    int egrp = t >> 4, c = t & 15;        // c = quad index (cols 4c..4c+3)
    const char* hb = (const char*)h1p;
    for (int i0 = 0; i0 < cb; i0 += 64) {
        int eA = i0 + egrp, eB = i0 + 32 + egrp;
        bool vA = eA < cb, vB = eB < cb;
        int2 rA = rbase[vA ? eA : 0];
        int2 rB = rbase[vB ? eB : 0];
        int sA = rA.x & 0x1FFFF, sB = rB.x & 0x1FFFF;
        int dA = (rA.x >> 17) & 127, dB = (rB.x >> 17) & 127;
        float cfA = vA ? __int_as_float(rA.y) * dinv[sA] : 0.f;
        float cfB = vB ? __int_as_float(rB.y) * dinv[sB] : 0.f;
        uint2 qA = *(const uint2*)(hb + sA * 128 + (c << 3));
        uint2 qB = *(const uint2*)(hb + sB * 128 + (c << 3));
        float* aA = acc + dA * 64 + (c << 2);
        float* aB = acc + dB * 64 + (c << 2);
        int rotA = (c + dA) & 3, rotB = (c + dB) & 3;
        float vA0 = bflo(qA.x) * cfA, vA1 = bfhi(qA.x) * cfA;
        float vA2 = bflo(qA.y) * cfA, vA3 = bfhi(qA.y) * cfA;
        float vB0 = bflo(qB.x) * cfB, vB1 = bfhi(qB.x) * cfB;
        float vB2 = bflo(qB.y) * cfB, vB3 = bfhi(qB.y) * cfB;
        // logical l stored at physical (l + rot) & 3 within the quad
        atomicAdd(aA + ((0 + rotA) & 3), vA0);
        atomicAdd(aA + ((1 + rotA) & 3), vA1);
        atomicAdd(aA + ((2 + rotA) & 3), vA2);
        atomicAdd(aA + ((3 + rotA) & 3), vA3);
        atomicAdd(aB + ((0 + rotB) & 3), vB0);
        atomicAdd(aB + ((1 + rotB) & 3), vB1);
        atomicAdd(aB + ((2 + rotB) & 3), vB2);
        atomicAdd(aB + ((3 + rotB) & 3), vB3);
    }
    __syncthreads();
    // writeout: out = dinv[n] * (acc + dinv[n] * h1[n])  (self-loop + dst scaling)
    int n = t >> 2, node = b * BSZ2 + n;
    if (node < N_NODES) {
        float dn = dinv[node];
        int cb4 = (t & 3) << 4;           // col base 0/16/32/48
        const uint2* hp = (const uint2*)(hb + (long)node * 128 + (cb4 << 1));
        float* ap = acc + n * 64 + cb4;
        float* op = agg1 + (long)node * 64 + cb4;
#pragma unroll
        for (int k = 0; k < 4; ++k) {
            int qq = (cb4 >> 2) + k;      // absolute quad index 0..15
            int rot = (qq + n) & 3;
            float f0 = ap[k * 4 + 0], f1 = ap[k * 4 + 1];
            float f2 = ap[k * 4 + 2], f3 = ap[k * 4 + 3];
            float fr[4] = {f0, f1, f2, f3};
            float l0 = fr[(0 + rot) & 3], l1 = fr[(1 + rot) & 3];
            float l2 = fr[(2 + rot) & 3], l3 = fr[(3 + rot) & 3];
            uint2 q = hp[k];
            float4 o;
            o.x = dn * (l0 + dn * bflo(q.x));
            o.y = dn * (l1 + dn * bfhi(q.x));
            o.z = dn * (l2 + dn * bflo(q.y));
            o.w = dn * (l3 + dn * bfhi(q.y));
            *(float4*)(op + k * 4) = o;
        }
    }
}

// ---------- h2 = relu(agg1 + b1) @ W2 via MFMA (UNscaled), bf16, 80B packed rows ----------
__global__ __launch_bounds__(256) void k_mm2(const float* __restrict__ agg1,
                                             const float* __restrict__ b1,
                                             const float* __restrict__ W2,
                                             unsigned short* __restrict__ h2p) {
    int t = threadIdx.x, lane = t & 63, wv = t >> 6;
    int m = lane & 15, quad = lane >> 4;
    int wid = blockIdx.x * 4 + wv, nw = gridDim.x * 4;
    shortx8 B[2][3];
#pragma unroll
    for (int kc = 0; kc < 2; ++kc)
#pragma unroll
        for (int tt = 0; tt < 3; ++tt) {
            int n = tt * 16 + m;
#pragma unroll
            for (int j = 0; j < 8; ++j) {
                int k = kc * 32 + quad * 8 + j;
                B[kc][tt][j] = (n < C_DIM) ? (short)f2bf(W2[k * C_DIM + n]) : (short)0;
            }
        }
    floatx4 ba0 = ((const floatx4*)(b1 + quad * 8))[0];
    floatx4 ba1 = ((const floatx4*)(b1 + quad * 8 + 4))[0];
    floatx4 bb0 = ((const floatx4*)(b1 + 32 + quad * 8))[0];
    floatx4 bb1 = ((const floatx4*)(b1 + 32 + quad * 8 + 4))[0];
    for (int g = wid; g < NGROUPS; g += nw) {
        int n0 = g * 16;
        const float* xr = agg1 + (long)(n0 + m) * 64 + quad * 8;
        floatx4 xa = ((const floatx4*)xr)[0];
        floatx4 xb = ((const floatx4*)(xr + 4))[0];
        floatx4 xc = ((const floatx4*)(xr + 32))[0];
        floatx4 xd = ((const floatx4*)(xr + 36))[0];
        shortx8 A0, A1;
#pragma unroll
        for (int j = 0; j < 4; ++j) {
            A0[j]     = (short)f2bf(fmaxf(xa[j] + ba0[j], 0.f));
            A0[4 + j] = (short)f2bf(fmaxf(xb[j] + ba1[j], 0.f));
            A1[j]     = (short)f2bf(fmaxf(xc[j] + bb0[j], 0.f));
            A1[4 + j] = (short)f2bf(fmaxf(xd[j] + bb1[j], 0.f));
        }
        floatx4 acc[3];
#pragma unroll
        for (int tt = 0; tt < 3; ++tt) {
            acc[tt] = (floatx4){0.f, 0.f, 0.f, 0.f};
            acc[tt] = __builtin_amdgcn_mfma_f32_16x16x32_bf16(A0, B[0][tt], acc[tt], 0, 0, 0);
            acc[tt] = __builtin_amdgcn_mfma_f32_16x16x32_bf16(A1, B[1][tt], acc[tt], 0, 0, 0);
        }
#pragma unroll
        for (int reg = 0; reg < 4; ++reg) {
            int node = n0 + quad * 4 + reg;
#pragma unroll
            for (int tt = 0; tt < 3; ++tt) {
                int col = tt * 16 + m;
                if (col < C_DIM)
                    h2p[(long)node * 40 + col] = f2bf(acc[tt][reg]);
            }
        }
    }
}

// ---------- agg2: LDS-atomic bucket accumulation (128 x 40 f32 = 20KB) + fused softmax ----------
__global__ __launch_bounds__(512) void k_agg2b(const int* __restrict__ cnt,
                                               const int2* __restrict__ rec,
                                               const float* __restrict__ dinv,
                                               const unsigned short* __restrict__ h2p,
                                               const float* __restrict__ b2,
                                               float* __restrict__ out) {
    __shared__ float acc[BSZ2 * 40];      // 20 KB
    int t = threadIdx.x, b = blockIdx.x;
    for (int i = t; i < BSZ2 * 40; i += 512) acc[i] = 0.f;
    __syncthreads();
    int cb = min(cnt[b], CAP);
    const int2* rbase = rec + (long)b * CAP;
    int lane = t & 63, wv = t >> 6;
    int eslot = lane / 20;                // 0..3 (3 = idle lane)
    int c = lane - eslot * 20;            // col pair index 0..19
    bool el = eslot < 3;
    const char* hb = (const char*)h2p;
    for (int i0 = 0; i0 < cb; i0 += 48) { // 8 waves x 3 edges x 2 slots
        int eA = i0 + wv * 3 + eslot, eB = eA + 24;
        bool vA = el && eA < cb, vB = el && eB < cb;
        int2 rA = rbase[vA ? eA : 0];
        int2 rB = rbase[vB ? eB : 0];
        int sA = rA.x & 0x1FFFF, sB = rB.x & 0x1FFFF;
        int dA = (rA.x >> 17) & 127, dB = (rB.x >> 17) & 127;
        float cfA = vA ? __int_as_float(rA.y) * dinv[sA] : 0.f;
        float cfB = vB ? __int_as_float(rB.y) * dinv[sB] : 0.f;
        unsigned int qA = *(const unsigned int*)(hb + sA * 80 + (c << 2));
        unsigned int qB = *(const unsigned int*)(hb + sB * 80 + (c << 2));
        atomicAdd(acc + dA * 40 + (c << 1),     bflo(qA) * cfA);
        atomicAdd(acc + dA * 40 + (c << 1) + 1, bfhi(qA) * cfA);
        atomicAdd(acc + dB * 40 + (c << 1),     bflo(qB) * cfB);
        atomicAdd(acc + dB * 40 + (c << 1) + 1, bfhi(qB) * cfB);
    }
    __syncthreads();
    // epilogue: 4 threads per node, 10 cols each; bias + self-loop + dinv + log_softmax
    int n = t >> 2, node = b * BSZ2 + n;
    if (node >= N_NODES) return;
    int part = t & 3;
    float dn = dinv[node];
    const unsigned int* hp = (const unsigned int*)(hb + (long)node * 80 + part * 20);
    float* ap = acc + n * 40 + part * 10;
    const float* bp = b2 + part * 10;
    float v[10];
    float mx = -INFINITY;
#pragma unroll
    for (int k = 0; k < 5; ++k) {
        unsigned int q = hp[k];
        float v0 = dn * (ap[2 * k]     + dn * bflo(q)) + bp[2 * k];
        float v1 = dn * (ap[2 * k + 1] + dn * bfhi(q)) + bp[2 * k + 1];
        v[2 * k] = v0; v[2 * k + 1] = v1;
        mx = fmaxf(mx, fmaxf(v0, v1));
    }
    mx = fmaxf(mx, __shfl_xor(mx, 1, 64));
    mx = fmaxf(mx, __shfl_xor(mx, 2, 64));
    const float LOG2E = 1.4426950408889634f;
    float s = 0.f;
#pragma unroll
    for (int k = 0; k < 10; ++k) s += __builtin_amdgcn_exp2f((v[k] - mx) * LOG2E);
    s += __shfl_xor(s, 1, 64);
    s += __shfl_xor(s, 2, 64);
    float ls = mx + __builtin_amdgcn_logf(s) * 0.6931471805599453f;
    float* op = out + (long)node * 40 + part * 10;
#pragma unroll
    for (int k = 0; k < 5; ++k)
        *(float2*)(op + 2 * k) = make_float2(v[2 * k] - ls, v[2 * k + 1] - ls);
}

extern "C" void kernel_launch(void* const* d_in, const int* in_sizes, int n_in,
                              void* d_out, int out_size, void* d_ws, size_t ws_size,
                              hipStream_t stream) {
    const float* x  = (const float*)d_in[0];
    const int*   ei = (const int*)d_in[1];
    const float* w  = (const float*)d_in[2];
    const float* W1 = (const float*)d_in[3];
    const float* b1 = (const float*)d_in[4];
    const float* W2 = (const float*)d_in[5];
    const float* b2 = (const float*)d_in[6];
    float* out = (float*)d_out;

    float* wsf = (float*)d_ws;
    int*   wsi = (int*)d_ws;
    float* deg  = wsf + OFF_DEG;          // becomes dinv after k_dinv
    int*   cnt  = wsi + OFF_CNT;
    int2*  rec  = (int2*)(wsi + OFF_REC);
    unsigned short* h1p = (unsigned short*)(wsi + OFF_H1P);
    unsigned short* h2p = (unsigned short*)(wsi + OFF_H2P);
    float* agg1 = wsf + OFF_AGG1;

    // zero deg[100000] + cnt[800] in one contiguous memset
    hipMemsetAsync(d_ws, 0, (100000 + 800) * sizeof(int), stream);

    k_mm1<<<512, 256, 0, stream>>>(x, W1, h1p);                 // independent of graph
    k_scatter2<<<NBE, 512, 0, stream>>>(ei, w, deg, cnt, rec);  // deg + bucket scatter
    k_dinv<<<196, 512, 0, stream>>>(deg);
    k_agg1b<<<NB2, 512, 0, stream>>>(cnt, rec, deg, h1p, agg1);
    k_mm2<<<512, 256, 0, stream>>>(agg1, b1, W2, h2p);
    k_agg2b<<<NB2, 512, 0, stream>>>(cnt, rec, deg, h2p, b2, out);
}

// Round 3
// 465.351 us; speedup vs baseline: 3.6650x; 3.6650x over previous
//
#include <hip/hip_runtime.h>
#include <math.h>

#define N_NODES 100000
#define N_EDGES 1600000
#define C_DIM 40
#define NGROUPS 6250                      // 100000 / 16 exactly

#define EGB 3125                          // edge-grid blocks (512 thr): 1.6M/512
#define NSB 98                            // scan blocks: ceil(100000/1024)

// ---------------- workspace layout (4-byte units) ----------------
#define OFF_DEGC 0                        // int[100000]
#define OFF_WDEG 100000                   // float[100000]
#define OFF_ROW  200000                   // int[100001]
#define OFF_CUR  300004                   // int[100000]
#define OFF_DINV 400004                   // float[100000]
#define OFF_BS   500004                   // int[128] block sums
#define OFF_REC2 500132                   // int2[E] (even -> 8B aligned)
#define OFF_H1P  3700132                  // ushort[N*64] bf16 h1', 128B rows
#define OFF_H2A  6900132                  // ushort[N*32] bf16 h2' cols 0-31, 64B rows
#define OFF_H2B  8500132                  // ushort[N*8]  bf16 h2' cols 32-39, 16B rows
#define OFF_AGG1 8900132                  // float[N*64]

typedef float floatx4 __attribute__((ext_vector_type(4)));
typedef short shortx8 __attribute__((ext_vector_type(8)));

__device__ inline unsigned short f2bf(float f) {
    unsigned int u = __float_as_uint(f);
    u += 0x7FFF + ((u >> 16) & 1);        // round to nearest even
    return (unsigned short)(u >> 16);
}
__device__ inline float bflo(unsigned int u) { return __uint_as_float(u << 16); }
__device__ inline float bfhi(unsigned int u) { return __uint_as_float(u & 0xFFFF0000u); }

// ---------- per-node degree (int) + weighted degree (float), global atomics ----------
__global__ __launch_bounds__(512) void k_deg(const int* __restrict__ ei,
                                             const float* __restrict__ w,
                                             int* __restrict__ degc,
                                             float* __restrict__ wdeg) {
    int e = blockIdx.x * 512 + threadIdx.x;
    if (e < N_EDGES) {
        int d = ei[N_EDGES + e];
        atomicAdd(&degc[d], 1);
        atomicAdd(&wdeg[d], w[e]);
    }
}

// ---------- scan 1: block-local exclusive scan of degc, emit block sums ----------
__global__ __launch_bounds__(1024) void k_scan1(const int* __restrict__ degc,
                                                int* __restrict__ rowStart,
                                                int* __restrict__ blockSum) {
    __shared__ int sd[1024];
    int t = threadIdx.x, b = blockIdx.x, i = b * 1024 + t;
    int v = (i < N_NODES) ? degc[i] : 0;
    sd[t] = v;
    __syncthreads();
    for (int off = 1; off < 1024; off <<= 1) {
        int u = (t >= off) ? sd[t - off] : 0;
        __syncthreads();
        sd[t] += u;
        __syncthreads();
    }
    if (i < N_NODES) rowStart[i] = sd[t] - v;
    if (t == 1023) blockSum[b] = sd[t];
}

// ---------- scan 2: single-block exclusive scan of the 98 block sums ----------
__global__ __launch_bounds__(128) void k_scan2(int* __restrict__ blockSum) {
    __shared__ int sd[128];
    int t = threadIdx.x;
    int v = (t < NSB) ? blockSum[t] : 0;
    sd[t] = v;
    __syncthreads();
    for (int off = 1; off < 128; off <<= 1) {
        int u = (t >= off) ? sd[t - off] : 0;
        __syncthreads();
        sd[t] += u;
        __syncthreads();
    }
    if (t < NSB) blockSum[t] = sd[t] - v;
}

// ---------- scan 3: finalize rowStart, init cursors, dinv = rsqrt(1 + wdeg) ----------
__global__ __launch_bounds__(1024) void k_scan3(int* __restrict__ rowStart,
                                                const int* __restrict__ blockSum,
                                                int* __restrict__ cur,
                                                const float* __restrict__ wdeg,
                                                float* __restrict__ dinv) {
    int t = threadIdx.x, b = blockIdx.x, i = b * 1024 + t;
    if (i < N_NODES) {
        int r = rowStart[i] + blockSum[b];
        rowStart[i] = r;
        cur[i] = r;
        dinv[i] = rsqrtf(1.f + wdeg[i]);
    }
    if (i == 0) rowStart[N_NODES] = N_EDGES;
}

// ---------- place edges directly into CSR slots (per-node atomic cursor) ----------
__global__ __launch_bounds__(512) void k_place(const int* __restrict__ ei,
                                               const float* __restrict__ w,
                                               int* __restrict__ cur,
                                               const float* __restrict__ dinv,
                                               int2* __restrict__ rec2) {
    int e = blockIdx.x * 512 + threadIdx.x;
    if (e < N_EDGES) {
        int s = ei[e], d = ei[N_EDGES + e];
        float cpart = w[e] * dinv[d];               // w * dinv[dst]
        int pos = atomicAdd(&cur[d], 1);
        rec2[pos] = make_int2(s << 7, __float_as_int(cpart));  // src byte-offset (128B rows)
    }
}

// ---------- h1' = (x @ W1) * dinv[row] via MFMA, stored bf16, 128B rows ----------
__global__ __launch_bounds__(256) void k_mm1(const float* __restrict__ x,
                                             const float* __restrict__ W1,
                                             const float* __restrict__ dinv,
                                             unsigned short* __restrict__ h1p) {
    int t = threadIdx.x, lane = t & 63, wv = t >> 6;
    int m = lane & 15, quad = lane >> 4;
    int wid = blockIdx.x * 4 + wv, nw = gridDim.x * 4;
    shortx8 B[2][4];
#pragma unroll
    for (int kc = 0; kc < 2; ++kc)
#pragma unroll
        for (int tt = 0; tt < 4; ++tt)
#pragma unroll
            for (int j = 0; j < 8; ++j) {
                int k = kc * 32 + quad * 8 + j;
                B[kc][tt][j] = (short)f2bf(W1[k * 64 + tt * 16 + m]);
            }
    for (int g = wid; g < NGROUPS; g += nw) {
        int n0 = g * 16;
        const float* xr = x + (long)(n0 + m) * 64 + quad * 8;
        floatx4 xa = ((const floatx4*)xr)[0];
        floatx4 xb = ((const floatx4*)(xr + 4))[0];
        floatx4 xc = ((const floatx4*)(xr + 32))[0];
        floatx4 xd = ((const floatx4*)(xr + 36))[0];
        shortx8 A0, A1;
#pragma unroll
        for (int j = 0; j < 4; ++j) {
            A0[j] = (short)f2bf(xa[j]);
            A0[4 + j] = (short)f2bf(xb[j]);
            A1[j] = (short)f2bf(xc[j]);
            A1[4 + j] = (short)f2bf(xd[j]);
        }
        floatx4 acc[4];
#pragma unroll
        for (int tt = 0; tt < 4; ++tt) {
            acc[tt] = (floatx4){0.f, 0.f, 0.f, 0.f};
            acc[tt] = __builtin_amdgcn_mfma_f32_16x16x32_bf16(A0, B[0][tt], acc[tt], 0, 0, 0);
            acc[tt] = __builtin_amdgcn_mfma_f32_16x16x32_bf16(A1, B[1][tt], acc[tt], 0, 0, 0);
        }
        floatx4 dv = ((const floatx4*)(dinv + n0 + quad * 4))[0];
#pragma unroll
        for (int reg = 0; reg < 4; ++reg) {
            int node = n0 + quad * 4 + reg;
            float d = dv[reg];
#pragma unroll
            for (int tt = 0; tt < 4; ++tt)
                h1p[(long)node * 64 + tt * 16 + m] = f2bf(acc[tt][reg] * d);
        }
    }
}

// ---------- agg1: 4 edge-slots x 16 lanes, 20-edge predicated unroll ----------
__global__ __launch_bounds__(256) void k_agg1(const int* __restrict__ rowStart,
                                              const int2* __restrict__ rec2,
                                              const float* __restrict__ dinv,
                                              const unsigned short* __restrict__ h1p,
                                              float* __restrict__ agg1) {
    __shared__ int2 cache[4][64];
    int t = threadIdx.x, lane = t & 63, wv = t >> 6;
    int node = blockIdx.x * 4 + wv;
    if (node >= N_NODES) return;
    int2* wc = cache[wv];
    wc[lane] = make_int2(0, 0);
    const char* hb = (const char*)h1p;
    int eslot = lane >> 4;
    int c = lane & 15;
    int lo = c << 3;
    float dn = dinv[node];
    float a0 = 0.f, a1 = 0.f, a2 = 0.f, a3 = 0.f;
    float b0 = 0.f, b1 = 0.f, b2v = 0.f, b3 = 0.f;
    if (eslot == 0) {
        const unsigned int* sp = (const unsigned int*)(hb + ((long)node << 7) + lo);
        unsigned int u0 = sp[0], u1 = sp[1];
        a0 = bflo(u0) * dn; a1 = bfhi(u0) * dn;
        a2 = bflo(u1) * dn; a3 = bfhi(u1) * dn;
    }
    int s0 = rowStart[node], s1 = rowStart[node + 1];
    for (int base = s0; base < s1; base += 64) {
        int idx = base + lane;
        if (idx < s1) wc[lane] = rec2[idx];
        __builtin_amdgcn_wave_barrier();
        int cnt = min(64, s1 - base);
        for (int j = 0; j < cnt; j += 20) {
            int2 e0, e1, e2, e3, e4;
            float w0, w1, w2, w3, w4;
            { int jj = j + eslot;      bool v = jj < cnt; e0 = wc[v ? jj : j]; w0 = v ? __int_as_float(e0.y) : 0.f; }
            { int jj = j + 4 + eslot;  bool v = jj < cnt; e1 = wc[v ? jj : j]; w1 = v ? __int_as_float(e1.y) : 0.f; }
            { int jj = j + 8 + eslot;  bool v = jj < cnt; e2 = wc[v ? jj : j]; w2 = v ? __int_as_float(e2.y) : 0.f; }
            { int jj = j + 12 + eslot; bool v = jj < cnt; e3 = wc[v ? jj : j]; w3 = v ? __int_as_float(e3.y) : 0.f; }
            { int jj = j + 16 + eslot; bool v = jj < cnt; e4 = wc[v ? jj : j]; w4 = v ? __int_as_float(e4.y) : 0.f; }
            uint2 q0 = *(const uint2*)(hb + e0.x + lo);
            uint2 q1 = *(const uint2*)(hb + e1.x + lo);
            uint2 q2 = *(const uint2*)(hb + e2.x + lo);
            uint2 q3 = *(const uint2*)(hb + e3.x + lo);
            uint2 q4 = *(const uint2*)(hb + e4.x + lo);
            a0 = fmaf(bflo(q0.x), w0, a0); a1 = fmaf(bfhi(q0.x), w0, a1);
            a2 = fmaf(bflo(q0.y), w0, a2); a3 = fmaf(bfhi(q0.y), w0, a3);
            b0 = fmaf(bflo(q1.x), w1, b0); b1 = fmaf(bfhi(q1.x), w1, b1);
            b2v = fmaf(bflo(q1.y), w1, b2v); b3 = fmaf(bfhi(q1.y), w1, b3);
            a0 = fmaf(bflo(q2.x), w2, a0); a1 = fmaf(bfhi(q2.x), w2, a1);
            a2 = fmaf(bflo(q2.y), w2, a2); a3 = fmaf(bfhi(q2.y), w2, a3);
            b0 = fmaf(bflo(q3.x), w3, b0); b1 = fmaf(bfhi(q3.x), w3, b1);
            b2v = fmaf(bflo(q3.y), w3, b2v); b3 = fmaf(bfhi(q3.y), w3, b3);
            a0 = fmaf(bflo(q4.x), w4, a0); a1 = fmaf(bfhi(q4.x), w4, a1);
            a2 = fmaf(bflo(q4.y), w4, a2); a3 = fmaf(bfhi(q4.y), w4, a3);
        }
        __builtin_amdgcn_wave_barrier();
    }
    a0 += b0; a1 += b1; a2 += b2v; a3 += b3;
    a0 += __shfl_xor(a0, 16, 64); a0 += __shfl_xor(a0, 32, 64);
    a1 += __shfl_xor(a1, 16, 64); a1 += __shfl_xor(a1, 32, 64);
    a2 += __shfl_xor(a2, 16, 64); a2 += __shfl_xor(a2, 32, 64);
    a3 += __shfl_xor(a3, 16, 64); a3 += __shfl_xor(a3, 32, 64);
    if (eslot == 0) {
        *(float4*)(agg1 + ((long)node << 6) + (c << 2)) = make_float4(a0, a1, a2, a3);
    }
}

// ---------- h2' = (relu(agg1+b1) @ W2) * dinv via MFMA, split bf16 stores ----------
// cols 0-31 -> h2a (64B rows), cols 32-39 -> h2b (16B rows)
__global__ __launch_bounds__(256) void k_mm2(const float* __restrict__ agg1,
                                             const float* __restrict__ b1,
                                             const float* __restrict__ W2,
                                             const float* __restrict__ dinv,
                                             unsigned short* __restrict__ h2a,
                                             unsigned short* __restrict__ h2b) {
    int t = threadIdx.x, lane = t & 63, wv = t >> 6;
    int m = lane & 15, quad = lane >> 4;
    int wid = blockIdx.x * 4 + wv, nw = gridDim.x * 4;
    shortx8 B[2][3];
#pragma unroll
    for (int kc = 0; kc < 2; ++kc)
#pragma unroll
        for (int tt = 0; tt < 3; ++tt) {
            int n = tt * 16 + m;
#pragma unroll
            for (int j = 0; j < 8; ++j) {
                int k = kc * 32 + quad * 8 + j;
                B[kc][tt][j] = (n < C_DIM) ? (short)f2bf(W2[k * C_DIM + n]) : (short)0;
            }
        }
    floatx4 ba0 = ((const floatx4*)(b1 + quad * 8))[0];
    floatx4 ba1 = ((const floatx4*)(b1 + quad * 8 + 4))[0];
    floatx4 bb0 = ((const floatx4*)(b1 + 32 + quad * 8))[0];
    floatx4 bb1 = ((const floatx4*)(b1 + 32 + quad * 8 + 4))[0];
    for (int g = wid; g < NGROUPS; g += nw) {
        int n0 = g * 16;
        const float* xr = agg1 + (long)(n0 + m) * 64 + quad * 8;
        floatx4 xa = ((const floatx4*)xr)[0];
        floatx4 xb = ((const floatx4*)(xr + 4))[0];
        floatx4 xc = ((const floatx4*)(xr + 32))[0];
        floatx4 xd = ((const floatx4*)(xr + 36))[0];
        shortx8 A0, A1;
#pragma unroll
        for (int j = 0; j < 4; ++j) {
            A0[j]     = (short)f2bf(fmaxf(xa[j] + ba0[j], 0.f));
            A0[4 + j] = (short)f2bf(fmaxf(xb[j] + ba1[j], 0.f));
            A1[j]     = (short)f2bf(fmaxf(xc[j] + bb0[j], 0.f));
            A1[4 + j] = (short)f2bf(fmaxf(xd[j] + bb1[j], 0.f));
        }
        floatx4 acc[3];
#pragma unroll
        for (int tt = 0; tt < 3; ++tt) {
            acc[tt] = (floatx4){0.f, 0.f, 0.f, 0.f};
            acc[tt] = __builtin_amdgcn_mfma_f32_16x16x32_bf16(A0, B[0][tt], acc[tt], 0, 0, 0);
            acc[tt] = __builtin_amdgcn_mfma_f32_16x16x32_bf16(A1, B[1][tt], acc[tt], 0, 0, 0);
        }
        floatx4 dv = ((const floatx4*)(dinv + n0 + quad * 4))[0];
#pragma unroll
        for (int reg = 0; reg < 4; ++reg) {
            int node = n0 + quad * 4 + reg;
            float d = dv[reg];
            h2a[(long)node * 32 + m]      = f2bf(acc[0][reg] * d);
            h2a[(long)node * 32 + 16 + m] = f2bf(acc[1][reg] * d);
            if (m < 8)
                h2b[(long)node * 8 + m]   = f2bf(acc[2][reg] * d);
        }
    }
}

// ---------- agg2: 3 edge-slots x 20 lanes, 21-edge predicated unroll + softmax ----------
// lanes c<16 gather from h2a (64B rows), c>=16 from h2b (16B rows, L2-resident)
__global__ __launch_bounds__(256) void k_agg2(const int* __restrict__ rowStart,
                                              const int2* __restrict__ rec2,
                                              const float* __restrict__ dinv,
                                              const unsigned short* __restrict__ h2a,
                                              const unsigned short* __restrict__ h2b,
                                              const float* __restrict__ b2,
                                              float* __restrict__ out) {
    __shared__ int2 cache[4][64];
    int t = threadIdx.x, lane = t & 63, wv = t >> 6;
    int node = blockIdx.x * 4 + wv;
    if (node >= N_NODES) return;
    int2* wc = cache[wv];
    wc[lane] = make_int2(0, 0);
    int eslot = lane / 20;
    int c = lane - eslot * 20;
    bool elane = eslot < 3;
    // per-lane gather base/shift: e.x = src*128; h2a byte = src*64 = e.x>>1;
    // h2b byte = src*16 = e.x>>3
    const char* gb = (c < 16) ? (const char*)h2a : (const char*)h2b;
    int sh = (c < 16) ? 1 : 3;
    int lo2 = (c < 16) ? (c << 2) : ((c - 16) << 2);
    float dn = dinv[node];
    float alo0 = 0.f, ahi0 = 0.f, alo1 = 0.f, ahi1 = 0.f;
    if (eslot == 0) {
        unsigned int u = *(const unsigned int*)(gb + (((long)node << 7) >> sh) + lo2);
        alo0 = bflo(u) * dn;
        ahi0 = bfhi(u) * dn;
    }
    int s0 = rowStart[node], s1 = rowStart[node + 1];
    for (int base = s0; base < s1; base += 64) {
        int idx = base + lane;
        if (idx < s1) wc[lane] = rec2[idx];
        __builtin_amdgcn_wave_barrier();
        int cnt = min(64, s1 - base);
        for (int j = 0; j < cnt; j += 21) {
            int2 e0, e1, e2, e3, e4, e5, e6;
            float f0, f1, f2, f3, f4, f5, f6;
            { int jj = j + eslot;      bool v = elane && jj < cnt; e0 = wc[v ? jj : j]; f0 = v ? __int_as_float(e0.y) : 0.f; }
            { int jj = j + 3 + eslot;  bool v = elane && jj < cnt; e1 = wc[v ? jj : j]; f1 = v ? __int_as_float(e1.y) : 0.f; }
            { int jj = j + 6 + eslot;  bool v = elane && jj < cnt; e2 = wc[v ? jj : j]; f2 = v ? __int_as_float(e2.y) : 0.f; }
            { int jj = j + 9 + eslot;  bool v = elane && jj < cnt; e3 = wc[v ? jj : j]; f3 = v ? __int_as_float(e3.y) : 0.f; }
            { int jj = j + 12 + eslot; bool v = elane && jj < cnt; e4 = wc[v ? jj : j]; f4 = v ? __int_as_float(e4.y) : 0.f; }
            { int jj = j + 15 + eslot; bool v = elane && jj < cnt; e5 = wc[v ? jj : j]; f5 = v ? __int_as_float(e5.y) : 0.f; }
            { int jj = j + 18 + eslot; bool v = elane && jj < cnt; e6 = wc[v ? jj : j]; f6 = v ? __int_as_float(e6.y) : 0.f; }
            unsigned int q0 = *(const unsigned int*)(gb + (e0.x >> sh) + lo2);
            unsigned int q1 = *(const unsigned int*)(gb + (e1.x >> sh) + lo2);
            unsigned int q2 = *(const unsigned int*)(gb + (e2.x >> sh) + lo2);
            unsigned int q3 = *(const unsigned int*)(gb + (e3.x >> sh) + lo2);
            unsigned int q4 = *(const unsigned int*)(gb + (e4.x >> sh) + lo2);
            unsigned int q5 = *(const unsigned int*)(gb + (e5.x >> sh) + lo2);
            unsigned int q6 = *(const unsigned int*)(gb + (e6.x >> sh) + lo2);
            alo0 = fmaf(bflo(q0), f0, alo0); ahi0 = fmaf(bfhi(q0), f0, ahi0);
            alo1 = fmaf(bflo(q1), f1, alo1); ahi1 = fmaf(bfhi(q1), f1, ahi1);
            alo0 = fmaf(bflo(q2), f2, alo0); ahi0 = fmaf(bfhi(q2), f2, ahi0);
            alo1 = fmaf(bflo(q3), f3, alo1); ahi1 = fmaf(bfhi(q3), f3, ahi1);
            alo0 = fmaf(bflo(q4), f4, alo0); ahi0 = fmaf(bfhi(q4), f4, ahi0);
            alo1 = fmaf(bflo(q5), f5, alo1); ahi1 = fmaf(bfhi(q5), f5, ahi1);
            alo0 = fmaf(bflo(q6), f6, alo0); ahi0 = fmaf(bfhi(q6), f6, ahi0);
        }
        __builtin_amdgcn_wave_barrier();
    }
    float alo = alo0 + alo1, ahi = ahi0 + ahi1;
    float t1 = __shfl(alo, lane + 20, 64), t2 = __shfl(alo, lane + 40, 64);
    float t3 = __shfl(ahi, lane + 20, 64), t4 = __shfl(ahi, lane + 40, 64);
    alo = alo + t1 + t2;
    ahi = ahi + t3 + t4;
    bool act = lane < 20;
    float2 bb = ((const float2*)b2)[c];
    float vlo = act ? alo + bb.x : -INFINITY;
    float vhi = act ? ahi + bb.y : -INFINITY;
    float m = fmaxf(vlo, vhi);
#pragma unroll
    for (int off = 16; off; off >>= 1) m = fmaxf(m, __shfl_xor(m, off, 64));
    const float LOG2E = 1.4426950408889634f;
    const float LN2   = 0.6931471805599453f;
    float exlo = act ? __builtin_amdgcn_exp2f((vlo - m) * LOG2E) : 0.f;
    float exhi = act ? __builtin_amdgcn_exp2f((vhi - m) * LOG2E) : 0.f;
    float s = exlo + exhi;
#pragma unroll
    for (int off = 16; off; off >>= 1) s += __shfl_xor(s, off, 64);
    float ls = m + __builtin_amdgcn_logf(s) * LN2;
    if (act) {
        *(float2*)(out + (long)node * C_DIM + (c << 1)) = make_float2(vlo - ls, vhi - ls);
    }
}

extern "C" void kernel_launch(void* const* d_in, const int* in_sizes, int n_in,
                              void* d_out, int out_size, void* d_ws, size_t ws_size,
                              hipStream_t stream) {
    const float* x  = (const float*)d_in[0];
    const int*   ei = (const int*)d_in[1];
    const float* w  = (const float*)d_in[2];
    const float* W1 = (const float*)d_in[3];
    const float* b1 = (const float*)d_in[4];
    const float* W2 = (const float*)d_in[5];
    const float* b2 = (const float*)d_in[6];
    float* out = (float*)d_out;

    float* wsf = (float*)d_ws;
    int*   wsi = (int*)d_ws;
    int*   degc     = wsi + OFF_DEGC;
    float* wdeg     = wsf + OFF_WDEG;
    int*   rowStart = wsi + OFF_ROW;
    int*   cur      = wsi + OFF_CUR;
    float* dinv     = wsf + OFF_DINV;
    int*   blockSum = wsi + OFF_BS;
    int2*  rec2     = (int2*)(wsi + OFF_REC2);
    unsigned short* h1p = (unsigned short*)(wsi + OFF_H1P);
    unsigned short* h2a = (unsigned short*)(wsi + OFF_H2A);
    unsigned short* h2b = (unsigned short*)(wsi + OFF_H2B);
    float* agg1     = wsf + OFF_AGG1;

    // zero degc[100000] + wdeg[100000] in one contiguous memset
    hipMemsetAsync(d_ws, 0, 200000 * sizeof(int), stream);

    // CSR build: degree -> scan -> place (global atomics, no sort)
    k_deg<<<EGB, 512, 0, stream>>>(ei, w, degc, wdeg);
    k_scan1<<<NSB, 1024, 0, stream>>>(degc, rowStart, blockSum);
    k_scan2<<<1, 128, 0, stream>>>(blockSum);
    k_scan3<<<NSB, 1024, 0, stream>>>(rowStart, blockSum, cur, wdeg, dinv);
    k_place<<<EGB, 512, 0, stream>>>(ei, w, cur, dinv, rec2);

    // layer 1 (MFMA matmul + gather-aggregate)
    k_mm1<<<512, 256, 0, stream>>>(x, W1, dinv, h1p);
    k_agg1<<<(N_NODES + 3) / 4, 256, 0, stream>>>(rowStart, rec2, dinv, h1p, agg1);

    // layer 2 (MFMA matmul + gather-aggregate + fused log-softmax)
    k_mm2<<<512, 256, 0, stream>>>(agg1, b1, W2, dinv, h2a, h2b);
    k_agg2<<<(N_NODES + 3) / 4, 256, 0, stream>>>(rowStart, rec2, dinv, h2a, h2b, b2, out);
}

// Round 4
// 266.458 us; speedup vs baseline: 6.4007x; 1.7464x over previous
//
#include <hip/hip_runtime.h>
#include <math.h>

#define N_NODES 100000
#define N_EDGES 1600000
#define C_DIM 40
#define NGROUPS 6250                      // 100000 / 16 exactly

#define BSZ 256                           // nodes per bucket
#define NB  ((N_NODES + BSZ - 1) / BSZ)   // 391
#define EB  4096                          // edges per hist/scatter block
#define NBE ((N_EDGES + EB - 1) / EB)     // 391

// ---------------- workspace layout (4-byte units) ----------------
#define OFF_DINV 0                        // float[100000]
#define OFF_BB   100000                   // int[NB+1]
#define OFF_CS   100392                   // int[NB] column sums
#define OFF_ROW  100800                   // int[N+1]
#define OFF_H    200802                   // int[NBE*NB]
#define OFF_REC2 353684                   // int2[E] sorted records (even -> 8B aligned)
#define OFF_H1P  3553684                  // ushort[N*64] bf16 h1'; unsorted rec aliases here
#define OFF_H2A  6753684                  // ushort[N*32] bf16 h2' cols 0-31, 64B rows
#define OFF_H2B  8353684                  // ushort[N*8]  bf16 h2' cols 32-39, 16B rows
#define OFF_AGG1 8753684                  // float[N*64]

typedef float floatx4 __attribute__((ext_vector_type(4)));
typedef short shortx8 __attribute__((ext_vector_type(8)));

__device__ inline unsigned short f2bf(float f) {
    unsigned int u = __float_as_uint(f);
    u += 0x7FFF + ((u >> 16) & 1);        // round to nearest even
    return (unsigned short)(u >> 16);
}
__device__ inline float bflo(unsigned int u) { return __uint_as_float(u << 16); }
__device__ inline float bfhi(unsigned int u) { return __uint_as_float(u & 0xFFFF0000u); }

// ---------- per-block bucket histogram: H[b][j] + global column sums ----------
__global__ __launch_bounds__(512) void k_hist2d(const int* __restrict__ ei,
                                                int* __restrict__ H,
                                                int* __restrict__ colsum) {
    __shared__ int bins[NB];
    int t = threadIdx.x, b = blockIdx.x;
    for (int i = t; i < NB; i += 512) bins[i] = 0;
    __syncthreads();
    int base = b * EB;
    for (int i = t; i < EB; i += 512) {
        int e = base + i;
        if (e < N_EDGES) atomicAdd(&bins[ei[N_EDGES + e] >> 8], 1);
    }
    __syncthreads();
    for (int i = t; i < NB; i += 512) {
        int c = bins[i];
        H[b * NB + i] = c;
        if (c) atomicAdd(&colsum[i], c);
    }
}

// ---------- column scan (self-computes bucketBase[j] from colsum) ----------
__global__ __launch_bounds__(512) void k_colscan(int* __restrict__ H,
                                                 const int* __restrict__ colsum,
                                                 int* __restrict__ bucketBase,
                                                 int* __restrict__ rowStart) {
    __shared__ int sd[512];
    __shared__ int sbase;
    int t = threadIdx.x, j = blockIdx.x;
    int p = 0;
    for (int i = t; i < j; i += 512) p += colsum[i];
    sd[t] = p;
    __syncthreads();
    for (int off = 256; off > 0; off >>= 1) {
        if (t < off) sd[t] += sd[t + off];
        __syncthreads();
    }
    if (t == 0) sbase = sd[0];
    __syncthreads();
    int base = sbase;
    if (t == 0) {
        bucketBase[j] = base;
        if (j == NB - 1) { bucketBase[NB] = base + colsum[j]; rowStart[N_NODES] = N_EDGES; }
    }
    __syncthreads();
    int val = (t < NBE) ? H[t * NB + j] : 0;
    sd[t] = val;
    __syncthreads();
    for (int off = 1; off < 512; off <<= 1) {
        int v = (t >= off) ? sd[t - off] : 0;
        __syncthreads();
        sd[t] += v;
        __syncthreads();
    }
    if (t < NBE) H[t * NB + j] = base + sd[t] - val;
}

// ---------- scatter into bucket regions (LDS cursors, no global atomics) ----------
__global__ __launch_bounds__(512) void k_scatter(const int* __restrict__ ei,
                                                 const float* __restrict__ w,
                                                 const int* __restrict__ blockBase,
                                                 int2* __restrict__ rec) {
    __shared__ int bases[NB];
    __shared__ int cur[NB];
    int t = threadIdx.x, b = blockIdx.x;
    for (int i = t; i < NB; i += 512) { bases[i] = blockBase[b * NB + i]; cur[i] = 0; }
    __syncthreads();
    int base = b * EB;
    for (int i = t; i < EB; i += 512) {
        int e = base + i;
        if (e < N_EDGES) {
            int s = ei[e], d = ei[N_EDGES + e];
            float wv = w[e];
            int bin = d >> 8;
            int pos = bases[bin] + atomicAdd(&cur[bin], 1);
            rec[pos] = make_int2(s | ((d & 255) << 17), __float_as_int(wv));
        }
    }
}

// ---------- per-bucket counting sort; payload = w*dinv[dst]; x = src byte-offset ----------
__global__ __launch_bounds__(512) void k_bsort(const int* __restrict__ bucketBase,
                                               const int2* __restrict__ rec,
                                               int2* __restrict__ rec2,
                                               float* __restrict__ dinv,
                                               int* __restrict__ rowStart) {
    __shared__ int   cnt[256];
    __shared__ float wsum[256];
    __shared__ int   cur[256];
    __shared__ int   sd[512];
    int t = threadIdx.x, b = blockIdx.x;
    if (t < 256) { cnt[t] = 0; wsum[t] = 0.f; }
    __syncthreads();
    int r0 = bucketBase[b], r1 = bucketBase[b + 1];
    for (int i = r0 + t; i < r1; i += 512) {
        int2 rv = rec[i];
        int l = (rv.x >> 17) & 255;
        atomicAdd(&cnt[l], 1);
        atomicAdd(&wsum[l], __int_as_float(rv.y));
    }
    __syncthreads();
    int val = (t < 256) ? cnt[t] : 0;
    sd[t] = val;
    __syncthreads();
    for (int off = 1; off < 512; off <<= 1) {
        int v = (t >= off) ? sd[t - off] : 0;
        __syncthreads();
        sd[t] += v;
        __syncthreads();
    }
    float dloc = 0.f;
    if (t < 256) {
        int excl = sd[t] - val;
        cur[t] = excl;
        int node = b * BSZ + t;
        dloc = rsqrtf(1.f + wsum[t]);
        if (node < N_NODES) {
            rowStart[node] = r0 + excl;
            dinv[node] = dloc;
        }
    }
    __syncthreads();
    if (t < 256) wsum[t] = dloc;
    __syncthreads();
    for (int i = r0 + t; i < r1; i += 512) {
        int2 rv = rec[i];
        int l = (rv.x >> 17) & 255;
        float cpart = __int_as_float(rv.y) * wsum[l];   // w * dinv[dst]
        int pos = r0 + atomicAdd(&cur[l], 1);
        rec2[pos] = make_int2((rv.x & 0x1FFFF) << 7, __float_as_int(cpart));  // src*128B
    }
}

// ---------- h1' = (x @ W1) * dinv[row] via MFMA, stored bf16, 128B rows ----------
__global__ __launch_bounds__(256) void k_mm1(const float* __restrict__ x,
                                             const float* __restrict__ W1,
                                             const float* __restrict__ dinv,
                                             unsigned short* __restrict__ h1p) {
    int t = threadIdx.x, lane = t & 63, wv = t >> 6;
    int m = lane & 15, quad = lane >> 4;
    int wid = blockIdx.x * 4 + wv, nw = gridDim.x * 4;
    shortx8 B[2][4];
#pragma unroll
    for (int kc = 0; kc < 2; ++kc)
#pragma unroll
        for (int tt = 0; tt < 4; ++tt)
#pragma unroll
            for (int j = 0; j < 8; ++j) {
                int k = kc * 32 + quad * 8 + j;
                B[kc][tt][j] = (short)f2bf(W1[k * 64 + tt * 16 + m]);
            }
    for (int g = wid; g < NGROUPS; g += nw) {
        int n0 = g * 16;
        const float* xr = x + (long)(n0 + m) * 64 + quad * 8;
        floatx4 xa = ((const floatx4*)xr)[0];
        floatx4 xb = ((const floatx4*)(xr + 4))[0];
        floatx4 xc = ((const floatx4*)(xr + 32))[0];
        floatx4 xd = ((const floatx4*)(xr + 36))[0];
        shortx8 A0, A1;
#pragma unroll
        for (int j = 0; j < 4; ++j) {
            A0[j] = (short)f2bf(xa[j]);
            A0[4 + j] = (short)f2bf(xb[j]);
            A1[j] = (short)f2bf(xc[j]);
            A1[4 + j] = (short)f2bf(xd[j]);
        }
        floatx4 acc[4];
#pragma unroll
        for (int tt = 0; tt < 4; ++tt) {
            acc[tt] = (floatx4){0.f, 0.f, 0.f, 0.f};
            acc[tt] = __builtin_amdgcn_mfma_f32_16x16x32_bf16(A0, B[0][tt], acc[tt], 0, 0, 0);
            acc[tt] = __builtin_amdgcn_mfma_f32_16x16x32_bf16(A1, B[1][tt], acc[tt], 0, 0, 0);
        }
        floatx4 dv = ((const floatx4*)(dinv + n0 + quad * 4))[0];
#pragma unroll
        for (int reg = 0; reg < 4; ++reg) {
            int node = n0 + quad * 4 + reg;
            float d = dv[reg];
#pragma unroll
            for (int tt = 0; tt < 4; ++tt)
                h1p[(long)node * 64 + tt * 16 + m] = f2bf(acc[tt][reg] * d);
        }
    }
}

// ---------- agg1: 4 edge-slots x 16 lanes, 20-edge predicated unroll ----------
__global__ __launch_bounds__(256) void k_agg1(const int* __restrict__ rowStart,
                                              const int2* __restrict__ rec2,
                                              const float* __restrict__ dinv,
                                              const unsigned short* __restrict__ h1p,
                                              float* __restrict__ agg1) {
    __shared__ int2 cache[4][64];
    int t = threadIdx.x, lane = t & 63, wv = t >> 6;
    int node = blockIdx.x * 4 + wv;
    if (node >= N_NODES) return;
    int2* wc = cache[wv];
    wc[lane] = make_int2(0, 0);
    const char* hb = (const char*)h1p;
    int eslot = lane >> 4;
    int c = lane & 15;
    int lo = c << 3;
    float dn = dinv[node];
    float a0 = 0.f, a1 = 0.f, a2 = 0.f, a3 = 0.f;
    float b0 = 0.f, b1 = 0.f, b2v = 0.f, b3 = 0.f;
    if (eslot == 0) {
        const unsigned int* sp = (const unsigned int*)(hb + ((long)node << 7) + lo);
        unsigned int u0 = sp[0], u1 = sp[1];
        a0 = bflo(u0) * dn; a1 = bfhi(u0) * dn;
        a2 = bflo(u1) * dn; a3 = bfhi(u1) * dn;
    }
    int s0 = rowStart[node], s1 = rowStart[node + 1];
    for (int base = s0; base < s1; base += 64) {
        int idx = base + lane;
        if (idx < s1) wc[lane] = rec2[idx];
        __builtin_amdgcn_wave_barrier();
        int cnt = min(64, s1 - base);
        for (int j = 0; j < cnt; j += 20) {
            int2 e0, e1, e2, e3, e4;
            float w0, w1, w2, w3, w4;
            { int jj = j + eslot;      bool v = jj < cnt; e0 = wc[v ? jj : j]; w0 = v ? __int_as_float(e0.y) : 0.f; }
            { int jj = j + 4 + eslot;  bool v = jj < cnt; e1 = wc[v ? jj : j]; w1 = v ? __int_as_float(e1.y) : 0.f; }
            { int jj = j + 8 + eslot;  bool v = jj < cnt; e2 = wc[v ? jj : j]; w2 = v ? __int_as_float(e2.y) : 0.f; }
            { int jj = j + 12 + eslot; bool v = jj < cnt; e3 = wc[v ? jj : j]; w3 = v ? __int_as_float(e3.y) : 0.f; }
            { int jj = j + 16 + eslot; bool v = jj < cnt; e4 = wc[v ? jj : j]; w4 = v ? __int_as_float(e4.y) : 0.f; }
            uint2 q0 = *(const uint2*)(hb + e0.x + lo);
            uint2 q1 = *(const uint2*)(hb + e1.x + lo);
            uint2 q2 = *(const uint2*)(hb + e2.x + lo);
            uint2 q3 = *(const uint2*)(hb + e3.x + lo);
            uint2 q4 = *(const uint2*)(hb + e4.x + lo);
            a0 = fmaf(bflo(q0.x), w0, a0); a1 = fmaf(bfhi(q0.x), w0, a1);
            a2 = fmaf(bflo(q0.y), w0, a2); a3 = fmaf(bfhi(q0.y), w0, a3);
            b0 = fmaf(bflo(q1.x), w1, b0); b1 = fmaf(bfhi(q1.x), w1, b1);
            b2v = fmaf(bflo(q1.y), w1, b2v); b3 = fmaf(bfhi(q1.y), w1, b3);
            a0 = fmaf(bflo(q2.x), w2, a0); a1 = fmaf(bfhi(q2.x), w2, a1);
            a2 = fmaf(bflo(q2.y), w2, a2); a3 = fmaf(bfhi(q2.y), w2, a3);
            b0 = fmaf(bflo(q3.x), w3, b0); b1 = fmaf(bfhi(q3.x), w3, b1);
            b2v = fmaf(bflo(q3.y), w3, b2v); b3 = fmaf(bfhi(q3.y), w3, b3);
            a0 = fmaf(bflo(q4.x), w4, a0); a1 = fmaf(bfhi(q4.x), w4, a1);
            a2 = fmaf(bflo(q4.y), w4, a2); a3 = fmaf(bfhi(q4.y), w4, a3);
        }
        __builtin_amdgcn_wave_barrier();
    }
    a0 += b0; a1 += b1; a2 += b2v; a3 += b3;
    a0 += __shfl_xor(a0, 16, 64); a0 += __shfl_xor(a0, 32, 64);
    a1 += __shfl_xor(a1, 16, 64); a1 += __shfl_xor(a1, 32, 64);
    a2 += __shfl_xor(a2, 16, 64); a2 += __shfl_xor(a2, 32, 64);
    a3 += __shfl_xor(a3, 16, 64); a3 += __shfl_xor(a3, 32, 64);
    if (eslot == 0) {
        *(float4*)(agg1 + ((long)node << 6) + (c << 2)) = make_float4(a0, a1, a2, a3);
    }
}

// ---------- h2' = (relu(agg1+b1) @ W2) * dinv via MFMA, split bf16 stores ----------
// cols 0-31 -> h2a (64B rows, 6.4MB), cols 32-39 -> h2b (16B rows, 1.6MB)
__global__ __launch_bounds__(256) void k_mm2(const float* __restrict__ agg1,
                                             const float* __restrict__ b1,
                                             const float* __restrict__ W2,
                                             const float* __restrict__ dinv,
                                             unsigned short* __restrict__ h2a,
                                             unsigned short* __restrict__ h2b) {
    int t = threadIdx.x, lane = t & 63, wv = t >> 6;
    int m = lane & 15, quad = lane >> 4;
    int wid = blockIdx.x * 4 + wv, nw = gridDim.x * 4;
    shortx8 B[2][3];
#pragma unroll
    for (int kc = 0; kc < 2; ++kc)
#pragma unroll
        for (int tt = 0; tt < 3; ++tt) {
            int n = tt * 16 + m;
#pragma unroll
            for (int j = 0; j < 8; ++j) {
                int k = kc * 32 + quad * 8 + j;
                B[kc][tt][j] = (n < C_DIM) ? (short)f2bf(W2[k * C_DIM + n]) : (short)0;
            }
        }
    floatx4 ba0 = ((const floatx4*)(b1 + quad * 8))[0];
    floatx4 ba1 = ((const floatx4*)(b1 + quad * 8 + 4))[0];
    floatx4 bb0 = ((const floatx4*)(b1 + 32 + quad * 8))[0];
    floatx4 bb1 = ((const floatx4*)(b1 + 32 + quad * 8 + 4))[0];
    for (int g = wid; g < NGROUPS; g += nw) {
        int n0 = g * 16;
        const float* xr = agg1 + (long)(n0 + m) * 64 + quad * 8;
        floatx4 xa = ((const floatx4*)xr)[0];
        floatx4 xb = ((const floatx4*)(xr + 4))[0];
        floatx4 xc = ((const floatx4*)(xr + 32))[0];
        floatx4 xd = ((const floatx4*)(xr + 36))[0];
        shortx8 A0, A1;
#pragma unroll
        for (int j = 0; j < 4; ++j) {
            A0[j]     = (short)f2bf(fmaxf(xa[j] + ba0[j], 0.f));
            A0[4 + j] = (short)f2bf(fmaxf(xb[j] + ba1[j], 0.f));
            A1[j]     = (short)f2bf(fmaxf(xc[j] + bb0[j], 0.f));
            A1[4 + j] = (short)f2bf(fmaxf(xd[j] + bb1[j], 0.f));
        }
        floatx4 acc[3];
#pragma unroll
        for (int tt = 0; tt < 3; ++tt) {
            acc[tt] = (floatx4){0.f, 0.f, 0.f, 0.f};
            acc[tt] = __builtin_amdgcn_mfma_f32_16x16x32_bf16(A0, B[0][tt], acc[tt], 0, 0, 0);
            acc[tt] = __builtin_amdgcn_mfma_f32_16x16x32_bf16(A1, B[1][tt], acc[tt], 0, 0, 0);
        }
        floatx4 dv = ((const floatx4*)(dinv + n0 + quad * 4))[0];
#pragma unroll
        for (int reg = 0; reg < 4; ++reg) {
            int node = n0 + quad * 4 + reg;
            float d = dv[reg];
            h2a[(long)node * 32 + m]      = f2bf(acc[0][reg] * d);
            h2a[(long)node * 32 + 16 + m] = f2bf(acc[1][reg] * d);
            if (m < 8)
                h2b[(long)node * 8 + m]   = f2bf(acc[2][reg] * d);
        }
    }
}

// ---------- agg2: 3 edge-slots x 20 lanes, 21-edge predicated unroll + softmax ----------
// lanes c<16 gather from h2a (64B rows), c>=16 from h2b (16B rows, mostly L2-resident)
__global__ __launch_bounds__(256) void k_agg2(const int* __restrict__ rowStart,
                                              const int2* __restrict__ rec2,
                                              const float* __restrict__ dinv,
                                              const unsigned short* __restrict__ h2a,
                                              const unsigned short* __restrict__ h2b,
                                              const float* __restrict__ b2,
                                              float* __restrict__ out) {
    __shared__ int2 cache[4][64];
    int t = threadIdx.x, lane = t & 63, wv = t >> 6;
    int node = blockIdx.x * 4 + wv;
    if (node >= N_NODES) return;
    int2* wc = cache[wv];
    wc[lane] = make_int2(0, 0);
    int eslot = lane / 20;
    int c = lane - eslot * 20;
    bool elane = eslot < 3;
    // rec2 e.x = src*128. h2a byte = src*64 = e.x>>1; h2b byte = src*16 = e.x>>3.
    const char* gb = (c < 16) ? (const char*)h2a : (const char*)h2b;
    int sh = (c < 16) ? 1 : 3;
    int lo2 = (c < 16) ? (c << 2) : ((c - 16) << 2);
    float dn = dinv[node];
    float alo0 = 0.f, ahi0 = 0.f, alo1 = 0.f, ahi1 = 0.f;
    if (eslot == 0) {
        unsigned int u = *(const unsigned int*)(gb + (((long)node << 7) >> sh) + lo2);
        alo0 = bflo(u) * dn;
        ahi0 = bfhi(u) * dn;
    }
    int s0 = rowStart[node], s1 = rowStart[node + 1];
    for (int base = s0; base < s1; base += 64) {
        int idx = base + lane;
        if (idx < s1) wc[lane] = rec2[idx];
        __builtin_amdgcn_wave_barrier();
        int cnt = min(64, s1 - base);
        for (int j = 0; j < cnt; j += 21) {
            int2 e0, e1, e2, e3, e4, e5, e6;
            float f0, f1, f2, f3, f4, f5, f6;
            { int jj = j + eslot;      bool v = elane && jj < cnt; e0 = wc[v ? jj : j]; f0 = v ? __int_as_float(e0.y) : 0.f; }
            { int jj = j + 3 + eslot;  bool v = elane && jj < cnt; e1 = wc[v ? jj : j]; f1 = v ? __int_as_float(e1.y) : 0.f; }
            { int jj = j + 6 + eslot;  bool v = elane && jj < cnt; e2 = wc[v ? jj : j]; f2 = v ? __int_as_float(e2.y) : 0.f; }
            { int jj = j + 9 + eslot;  bool v = elane && jj < cnt; e3 = wc[v ? jj : j]; f3 = v ? __int_as_float(e3.y) : 0.f; }
            { int jj = j + 12 + eslot; bool v = elane && jj < cnt; e4 = wc[v ? jj : j]; f4 = v ? __int_as_float(e4.y) : 0.f; }
            { int jj = j + 15 + eslot; bool v = elane && jj < cnt; e5 = wc[v ? jj : j]; f5 = v ? __int_as_float(e5.y) : 0.f; }
            { int jj = j + 18 + eslot; bool v = elane && jj < cnt; e6 = wc[v ? jj : j]; f6 = v ? __int_as_float(e6.y) : 0.f; }
            unsigned int q0 = *(const unsigned int*)(gb + (e0.x >> sh) + lo2);
            unsigned int q1 = *(const unsigned int*)(gb + (e1.x >> sh) + lo2);
            unsigned int q2 = *(const unsigned int*)(gb + (e2.x >> sh) + lo2);
            unsigned int q3 = *(const unsigned int*)(gb + (e3.x >> sh) + lo2);
            unsigned int q4 = *(const unsigned int*)(gb + (e4.x >> sh) + lo2);
            unsigned int q5 = *(const unsigned int*)(gb + (e5.x >> sh) + lo2);
            unsigned int q6 = *(const unsigned int*)(gb + (e6.x >> sh) + lo2);
            alo0 = fmaf(bflo(q0), f0, alo0); ahi0 = fmaf(bfhi(q0), f0, ahi0);
            alo1 = fmaf(bflo(q1), f1, alo1); ahi1 = fmaf(bfhi(q1), f1, ahi1);
            alo0 = fmaf(bflo(q2), f2, alo0); ahi0 = fmaf(bfhi(q2), f2, ahi0);
            alo1 = fmaf(bflo(q3), f3, alo1); ahi1 = fmaf(bfhi(q3), f3, ahi1);
            alo0 = fmaf(bflo(q4), f4, alo0); ahi0 = fmaf(bfhi(q4), f4, ahi0);
            alo1 = fmaf(bflo(q5), f5, alo1); ahi1 = fmaf(bfhi(q5), f5, ahi1);
            alo0 = fmaf(bflo(q6), f6, alo0); ahi0 = fmaf(bfhi(q6), f6, ahi0);
        }
        __builtin_amdgcn_wave_barrier();
    }
    float alo = alo0 + alo1, ahi = ahi0 + ahi1;
    float t1 = __shfl(alo, lane + 20, 64), t2 = __shfl(alo, lane + 40, 64);
    float t3 = __shfl(ahi, lane + 20, 64), t4 = __shfl(ahi, lane + 40, 64);
    alo = alo + t1 + t2;
    ahi = ahi + t3 + t4;
    bool act = lane < 20;
    float2 bb = ((const float2*)b2)[c];
    float vlo = act ? alo + bb.x : -INFINITY;
    float vhi = act ? ahi + bb.y : -INFINITY;
    float m = fmaxf(vlo, vhi);
#pragma unroll
    for (int off = 16; off; off >>= 1) m = fmaxf(m, __shfl_xor(m, off, 64));
    const float LOG2E = 1.4426950408889634f;
    const float LN2   = 0.6931471805599453f;
    float exlo = act ? __builtin_amdgcn_exp2f((vlo - m) * LOG2E) : 0.f;
    float exhi = act ? __builtin_amdgcn_exp2f((vhi - m) * LOG2E) : 0.f;
    float s = exlo + exhi;
#pragma unroll
    for (int off = 16; off; off >>= 1) s += __shfl_xor(s, off, 64);
    float ls = m + __builtin_amdgcn_logf(s) * LN2;
    if (act) {
        *(float2*)(out + (long)node * C_DIM + (c << 1)) = make_float2(vlo - ls, vhi - ls);
    }
}

extern "C" void kernel_launch(void* const* d_in, const int* in_sizes, int n_in,
                              void* d_out, int out_size, void* d_ws, size_t ws_size,
                              hipStream_t stream) {
    const float* x  = (const float*)d_in[0];
    const int*   ei = (const int*)d_in[1];
    const float* w  = (const float*)d_in[2];
    const float* W1 = (const float*)d_in[3];
    const float* b1 = (const float*)d_in[4];
    const float* W2 = (const float*)d_in[5];
    const float* b2 = (const float*)d_in[6];
    float* out = (float*)d_out;

    float* wsf = (float*)d_ws;
    int*   wsi = (int*)d_ws;
    float* dinv       = wsf + OFF_DINV;
    int*   bucketBase = wsi + OFF_BB;
    int*   colsum     = wsi + OFF_CS;
    int*   rowStart   = wsi + OFF_ROW;
    int*   H          = wsi + OFF_H;
    int2*  rec2       = (int2*)(wsi + OFF_REC2);
    int2*  rec        = (int2*)(wsi + OFF_H1P);              // dead before h1p written
    unsigned short* h1p = (unsigned short*)(wsi + OFF_H1P);
    unsigned short* h2a = (unsigned short*)(wsi + OFF_H2A);
    unsigned short* h2b = (unsigned short*)(wsi + OFF_H2B);
    float* agg1       = wsf + OFF_AGG1;

    // CSR build — zero global atomics except 391-bin colsum
    hipMemsetAsync(colsum, 0, NB * sizeof(int), stream);
    k_hist2d<<<NBE, 512, 0, stream>>>(ei, H, colsum);
    k_colscan<<<NB, 512, 0, stream>>>(H, colsum, bucketBase, rowStart);
    k_scatter<<<NBE, 512, 0, stream>>>(ei, w, H, rec);
    k_bsort<<<NB, 512, 0, stream>>>(bucketBase, rec, rec2, dinv, rowStart);

    // layer 1 (MFMA matmul + gather-aggregate)
    k_mm1<<<512, 256, 0, stream>>>(x, W1, dinv, h1p);
    k_agg1<<<(N_NODES + 3) / 4, 256, 0, stream>>>(rowStart, rec2, dinv, h1p, agg1);

    // layer 2 (MFMA matmul + gather-aggregate + fused log-softmax)
    k_mm2<<<512, 256, 0, stream>>>(agg1, b1, W2, dinv, h2a, h2b);
    k_agg2<<<(N_NODES + 3) / 4, 256, 0, stream>>>(rowStart, rec2, dinv, h2a, h2b, b2, out);
}